// Round 3
// baseline (219.352 us; speedup 1.0000x reference)
//
#include <hip/hip_runtime.h>
#include <hip/hip_bf16.h>

// LocalActivationUnit: score[b,t] = relu([q,k,q-k,q*k]·W0 + b0)·W1 + b1
// Folded form: Wb[e][h] = W0[128+e][h] - W0[256+e][h] + q[e]*W0[384+e][h]
//              bias[h]  = sum_e q[e]*(W0[e][h] + W0[256+e][h]) + b0[h]
//              h = relu(k·Wb + bias);  score = h·W1 + b1
//
// R7: two-stage split. Evidence from R6 rocprof: lau=60.7us at 4.9% HBM,
// FETCH only 24MB (keys are L3-resident) -> latency-bound, not BW-bound.
// Grid 1024 = only 16 waves/CU (half capacity); fold replicated on every
// block's critical path. Fix:
//   Stage A (fold_kernel, 1024 blocks): fold W0 with q -> WbT[64][136] bf16
//     + bias[64] f32 into workspace (17664 B/batch), coalesced uint4 copy-out.
//   Stage B (score_kernel, 2048 blocks = 2/batch, tiles 0-6|7-12,
//     __launch_bounds__(256,8)): LDS 17.9KB -> 8 blocks/CU = 32 waves/CU,
//     exactly resident (2048 = 8*256). Pure streamed MFMA loop, one barrier.
//     Per-wave pipelining dropped: VGPR must stay <=64 for 8 waves/SIMD;
//     latency hiding now comes from TLP (8 waves/SIMD), not ILP.

#define TB 200
#define EB 128
#define HB 64
#define WS_STRIDE 17664   // 64*136*2 (WbT) + 64*4 (bias)

typedef __attribute__((ext_vector_type(8))) short bf16x8;
typedef __attribute__((ext_vector_type(4))) float f32x4;

__global__ __launch_bounds__(256, 4)
void fold_kernel(const float* __restrict__ query,
                 const float* __restrict__ W0,
                 const float* __restrict__ b0,
                 unsigned char* __restrict__ ws)
{
    const int b   = blockIdx.x;
    const int tid = threadIdx.x;

    __shared__ float red2[HB][17];
    __shared__ float bias_s[HB];
    __shared__ __align__(16) __hip_bfloat16 wbt[HB][EB + 8];

    {
        const int hq = (tid & 15) * 4;      // h base: 0,4,...,60
        const int ck = tid >> 4;            // 0..15, each covers 8 e's
        const float4 q0 = *(const float4*)&query[(size_t)b * EB + ck * 8];
        const float4 q1 = *(const float4*)&query[(size_t)b * EB + ck * 8 + 4];
        const float qe_arr[8] = {q0.x, q0.y, q0.z, q0.w, q1.x, q1.y, q1.z, q1.w};
        float bp0 = 0.f, bp1 = 0.f, bp2 = 0.f, bp3 = 0.f;
        #pragma unroll
        for (int i = 0; i < 8; ++i) {
            const int e = ck * 8 + i;
            const float qe = qe_arr[i];
            const float4 wa = *(const float4*)&W0[(size_t)e            * HB + hq];
            const float4 wb = *(const float4*)&W0[(size_t)(EB + e)     * HB + hq];
            const float4 wc = *(const float4*)&W0[(size_t)(2 * EB + e) * HB + hq];
            const float4 wd = *(const float4*)&W0[(size_t)(3 * EB + e) * HB + hq];
            wbt[hq + 0][e] = __float2bfloat16(wb.x - wc.x + qe * wd.x);
            wbt[hq + 1][e] = __float2bfloat16(wb.y - wc.y + qe * wd.y);
            wbt[hq + 2][e] = __float2bfloat16(wb.z - wc.z + qe * wd.z);
            wbt[hq + 3][e] = __float2bfloat16(wb.w - wc.w + qe * wd.w);
            bp0 += qe * (wa.x + wc.x);
            bp1 += qe * (wa.y + wc.y);
            bp2 += qe * (wa.z + wc.z);
            bp3 += qe * (wa.w + wc.w);
        }
        red2[hq + 0][ck] = bp0;
        red2[hq + 1][ck] = bp1;
        red2[hq + 2][ck] = bp2;
        red2[hq + 3][ck] = bp3;
    }
    __syncthreads();
    if (tid < HB) {
        float s = b0[tid];
        #pragma unroll
        for (int c = 0; c < 16; ++c) s += red2[tid][c];
        bias_s[tid] = s;
    }
    __syncthreads();

    // coalesced copy-out: WbT (1088 uint4) + bias (16 uint4)
    uint4* dst = (uint4*)(ws + (size_t)b * WS_STRIDE);
    const uint4* srcW = (const uint4*)&wbt[0][0];
    #pragma unroll
    for (int k = 0; k < 4; ++k) dst[tid + k * 256] = srcW[tid + k * 256];
    if (tid < 64) dst[1024 + tid] = srcW[1024 + tid];
    if (tid < 16) dst[1088 + tid] = ((const uint4*)bias_s)[tid];
}

__global__ __launch_bounds__(256, 8)
void score_kernel(const float* __restrict__ keys,
                  const float* __restrict__ W1,
                  const float* __restrict__ b1,
                  const unsigned char* __restrict__ ws,
                  float* __restrict__ out)
{
    const int bid  = blockIdx.x;
    const int b    = bid >> 1;
    const int half = bid & 1;          // 0: tiles 0..6, 1: tiles 7..12
    const int tid  = threadIdx.x;
    const int lane = tid & 63;
    const int wave = tid >> 6;
    const int ln15 = lane & 15;
    const int quad = lane >> 4;

    __shared__ float bias_s[HB];
    __shared__ float w1_s[HB];
    // WbT[h][e] bf16, row stride 136 elems = 272 B. 272 % 128 == 16, so the
    // 16-byte ds_read_b128 fragments of lanes (ln15,quad) spread uniformly
    // across all 32 banks (structural minimum for b128).
    __shared__ __align__(16) __hip_bfloat16 wbt[HB][EB + 8];

    // coalesced LDS fill from workspace
    const uint4* src = (const uint4*)(ws + (size_t)b * WS_STRIDE);
    uint4* dstW = (uint4*)&wbt[0][0];
    #pragma unroll
    for (int k = 0; k < 4; ++k) dstW[tid + k * 256] = src[tid + k * 256];
    if (tid < 64) dstW[1024 + tid] = src[1024 + tid];
    if (tid < 64) {
        bias_s[tid] = ((const float*)(ws + (size_t)b * WS_STRIDE + 17408))[tid];
        w1_s[tid]   = W1[tid];
    }
    __syncthreads();

    float w1q[4], biasq[4];
    #pragma unroll
    for (int nt = 0; nt < 4; ++nt) {
        w1q[nt]   = w1_s[nt * 16 + ln15];
        biasq[nt] = bias_s[nt * 16 + ln15];
    }

    const __hip_bfloat16* wb_base = &wbt[ln15][quad * 8];
    const float* kb  = keys + (size_t)b * TB * EB;
    const float  b1v = b1[0];

    const int mtEnd = half ? 13 : 7;
    for (int mt = half * 7 + wave; mt < mtEnd; mt += 4) {
        const int mrow = mt * 16 + ln15;
        const int mc   = mrow < TB ? mrow : TB - 1;  // clamp: valid mem, masked at store
        const float* arow = kb + (size_t)mc * EB + quad * 8;

        float4 af[8];
        #pragma unroll
        for (int ks = 0; ks < 4; ++ks) {
            af[2*ks]   = *(const float4*)(arow + ks * 32);
            af[2*ks+1] = *(const float4*)(arow + ks * 32 + 4);
        }
        bf16x8 ab[4];
        #pragma unroll
        for (int ks = 0; ks < 4; ++ks) {
            union { bf16x8 v; __hip_bfloat162 h2[4]; } u;
            u.h2[0] = __float22bfloat162_rn(make_float2(af[2*ks].x,   af[2*ks].y));
            u.h2[1] = __float22bfloat162_rn(make_float2(af[2*ks].z,   af[2*ks].w));
            u.h2[2] = __float22bfloat162_rn(make_float2(af[2*ks+1].x, af[2*ks+1].y));
            u.h2[3] = __float22bfloat162_rn(make_float2(af[2*ks+1].z, af[2*ks+1].w));
            ab[ks] = u.v;
        }

        f32x4 acc[4] = {{0,0,0,0},{0,0,0,0},{0,0,0,0},{0,0,0,0}};
        #pragma unroll
        for (int ks = 0; ks < 4; ++ks) {
            #pragma unroll
            for (int nt = 0; nt < 4; ++nt) {
                const bf16x8 bf = *(const bf16x8*)(wb_base + nt * 16 * (EB + 8) + ks * 32);
                acc[nt] = __builtin_amdgcn_mfma_f32_16x16x32_bf16(ab[ks], bf, acc[nt], 0, 0, 0);
            }
        }

        // ---- epilogue: relu + bias, dot with W1, reduce over n (16 lanes) ----
        // C layout: n = ln15, m(in-tile) = quad*4 + r
        float part[4];
        #pragma unroll
        for (int r = 0; r < 4; ++r) {
            float s = 0.f;
            #pragma unroll
            for (int nt = 0; nt < 4; ++nt) {
                float hv = acc[nt][r] + biasq[nt];
                hv = hv > 0.f ? hv : 0.f;
                s += hv * w1q[nt];
            }
            part[r] = s;
        }
        #pragma unroll
        for (int m = 1; m < 16; m <<= 1) {
            #pragma unroll
            for (int r = 0; r < 4; ++r)
                part[r] += __shfl_xor(part[r], m, 64);
        }
        if (ln15 == 0) {
            #pragma unroll
            for (int r = 0; r < 4; ++r) {
                const int mg = mt * 16 + quad * 4 + r;
                if (mg < TB) out[(size_t)b * TB + mg] = part[r] + b1v;
            }
        }
    }
}

extern "C" void kernel_launch(void* const* d_in, const int* in_sizes, int n_in,
                              void* d_out, int out_size, void* d_ws, size_t ws_size,
                              hipStream_t stream) {
    const float* query = (const float*)d_in[0];
    const float* keys  = (const float*)d_in[1];
    const float* W0    = (const float*)d_in[2];
    const float* b0    = (const float*)d_in[3];
    const float* W1    = (const float*)d_in[4];
    const float* b1    = (const float*)d_in[5];
    float* out = (float*)d_out;
    unsigned char* ws = (unsigned char*)d_ws;

    fold_kernel<<<1024, 256, 0, stream>>>(query, W0, b0, ws);
    score_kernel<<<2048, 256, 0, stream>>>(keys, W1, b1, ws, out);
}

// Round 4
// 190.801 us; speedup vs baseline: 1.1496x; 1.1496x over previous
//
#include <hip/hip_runtime.h>
#include <hip/hip_bf16.h>

// LocalActivationUnit: score[b,t] = relu([q,k,q-k,q*k]·W0 + b0)·W1 + b1
// Folded form: Wb[e][h] = W0[128+e][h] - W0[256+e][h] + q[e]*W0[384+e][h]
//              bias[h]  = sum_e q[e]*(W0[e][h] + W0[256+e][h]) + b0[h]
//              h = relu(k·Wb + bias);  score = h·W1 + b1
// One block per batch b. Per-batch 200x128x64 bf16 MFMA GEMM.
//
// R8: revert to the R0/R4 structure (best measured: 48us kernel share; every
// later schedule change regressed) + ONE change: two-tile pairing. Evidence
// (R7 split): fold is ~3-6us, main loop is everything, VALUBusy 3.5% ->
// latency-exposure-bound with only 8 loads in flight per wave. Pairing issues
// 16 loads (two m-tiles) before the first vmcnt wait; tile B's latency hides
// under tile A's convert+MFMA+epilogue. No occupancy change (still (256,4),
// 1024 blocks exactly resident), no extra barriers, fold byte-identical to R0.

#define TB 200
#define EB 128
#define HB 64

typedef __attribute__((ext_vector_type(8))) short bf16x8;
typedef __attribute__((ext_vector_type(4))) float f32x4;

__global__ __launch_bounds__(256, 4)
void lau_kernel(const float* __restrict__ query,
                const float* __restrict__ keys,
                const float* __restrict__ W0,
                const float* __restrict__ b0,
                const float* __restrict__ W1,
                const float* __restrict__ b1,
                float* __restrict__ out)
{
    const int b   = blockIdx.x;
    const int tid = threadIdx.x;

    __shared__ float q_s[EB];
    __shared__ float bias_s[HB];
    __shared__ float w1_s[HB];
    __shared__ float red_s[256];
    // WbT[h][e] bf16, row stride 136 elems = 272 B. 272 % 128 == 16, so the
    // 16-byte ds_read_b128 fragments of lanes (ln15,quad) spread uniformly
    // across all 32 banks (structural minimum for b128).
    __shared__ __align__(16) __hip_bfloat16 wbt[HB][EB + 8];

    if (tid < EB) q_s[tid] = query[(size_t)b * EB + tid];
    __syncthreads();

    // ---- per-batch weight fold + bias partials (exact R0 form) ----
    {
        const int h     = tid & 63;
        const int chunk = tid >> 6;       // 0..3, each covers 32 e's
        float biasp = 0.f;
        #pragma unroll 8
        for (int i = 0; i < 32; ++i) {
            const int e = chunk * 32 + i;
            const float qe  = q_s[e];
            const float w0a = W0[(size_t)e            * HB + h];
            const float w0b = W0[(size_t)(EB + e)     * HB + h];
            const float w0c = W0[(size_t)(2 * EB + e) * HB + h];
            const float w0d = W0[(size_t)(3 * EB + e) * HB + h];
            wbt[h][e] = __float2bfloat16(w0b - w0c + qe * w0d);
            biasp += qe * (w0a + w0c);
        }
        red_s[tid] = biasp;
    }
    __syncthreads();
    if (tid < HB) {
        bias_s[tid] = red_s[tid] + red_s[tid + 64] + red_s[tid + 128] + red_s[tid + 192] + b0[tid];
        w1_s[tid]   = W1[tid];
    }
    __syncthreads();

    const int lane = tid & 63;
    const int wave = tid >> 6;
    const int ln15 = lane & 15;
    const int quad = lane >> 4;

    float w1q[4], biasq[4];
    #pragma unroll
    for (int nt = 0; nt < 4; ++nt) {
        w1q[nt]   = w1_s[nt * 16 + ln15];
        biasq[nt] = bias_s[nt * 16 + ln15];
    }

    // Per-lane LDS base for B-fragments: WbT[ln15][quad*8], nt adds 4352 B,
    // ks adds 64 B -> compiler folds into ds_read_b128 offsets.
    const __hip_bfloat16* wb_base = &wbt[ln15][quad * 8];

    const float* kb  = keys + (size_t)b * TB * EB;
    const float  b1v = b1[0];

    // 13 m-tiles of 16 rows cover T=200. Pairs p=0..6: tiles (2p, 2p+1);
    // pair 6 has only tile 12. Wave w takes pairs w, w+4.
    for (int p = wave; p < 7; p += 4) {
        const int mtA  = 2 * p;
        const int mtB  = 2 * p + 1;
        const bool hasB = (mtB < 13);

        // ---- issue BOTH tiles' loads before any wait (16 loads in flight) ----
        const int mrowA = mtA * 16 + ln15;
        const int mcA   = mrowA < TB ? mrowA : TB - 1;  // clamp: valid mem, masked at store
        const float* arowA = kb + (size_t)mcA * EB + quad * 8;
        float4 aA[8];
        #pragma unroll
        for (int ks = 0; ks < 4; ++ks) {
            aA[2*ks]   = *(const float4*)(arowA + ks * 32);
            aA[2*ks+1] = *(const float4*)(arowA + ks * 32 + 4);
        }
        float4 aB[8];
        if (hasB) {
            const int mrowB = mtB * 16 + ln15;
            const int mcB   = mrowB < TB ? mrowB : TB - 1;
            const float* arowB = kb + (size_t)mcB * EB + quad * 8;
            #pragma unroll
            for (int ks = 0; ks < 4; ++ks) {
                aB[2*ks]   = *(const float4*)(arowB + ks * 32);
                aB[2*ks+1] = *(const float4*)(arowB + ks * 32 + 4);
            }
        }

        // ---- tile A: convert (waits vmcnt(8)), MFMA, epilogue ----
        {
            f32x4 acc[4] = {{0,0,0,0},{0,0,0,0},{0,0,0,0},{0,0,0,0}};
            #pragma unroll
            for (int ks = 0; ks < 4; ++ks) {
                union { bf16x8 v; __hip_bfloat162 h2[4]; } u;
                u.h2[0] = __float22bfloat162_rn(make_float2(aA[2*ks].x,   aA[2*ks].y));
                u.h2[1] = __float22bfloat162_rn(make_float2(aA[2*ks].z,   aA[2*ks].w));
                u.h2[2] = __float22bfloat162_rn(make_float2(aA[2*ks+1].x, aA[2*ks+1].y));
                u.h2[3] = __float22bfloat162_rn(make_float2(aA[2*ks+1].z, aA[2*ks+1].w));
                #pragma unroll
                for (int nt = 0; nt < 4; ++nt) {
                    const bf16x8 bf = *(const bf16x8*)(wb_base + nt * 16 * (EB + 8) + ks * 32);
                    acc[nt] = __builtin_amdgcn_mfma_f32_16x16x32_bf16(u.v, bf, acc[nt], 0, 0, 0);
                }
            }
            float part[4];
            #pragma unroll
            for (int r = 0; r < 4; ++r) {
                float s = 0.f;
                #pragma unroll
                for (int nt = 0; nt < 4; ++nt) {
                    float hv = acc[nt][r] + biasq[nt];
                    hv = hv > 0.f ? hv : 0.f;
                    s += hv * w1q[nt];
                }
                part[r] = s;
            }
            #pragma unroll
            for (int m = 1; m < 16; m <<= 1) {
                #pragma unroll
                for (int r = 0; r < 4; ++r)
                    part[r] += __shfl_xor(part[r], m, 64);
            }
            if (ln15 == 0) {
                #pragma unroll
                for (int r = 0; r < 4; ++r) {
                    const int mg = mtA * 16 + quad * 4 + r;
                    if (mg < TB) out[(size_t)b * TB + mg] = part[r] + b1v;
                }
            }
        }

        // ---- tile B: convert (loads had ~full tile-A compute to land) ----
        if (hasB) {
            f32x4 acc[4] = {{0,0,0,0},{0,0,0,0},{0,0,0,0},{0,0,0,0}};
            #pragma unroll
            for (int ks = 0; ks < 4; ++ks) {
                union { bf16x8 v; __hip_bfloat162 h2[4]; } u;
                u.h2[0] = __float22bfloat162_rn(make_float2(aB[2*ks].x,   aB[2*ks].y));
                u.h2[1] = __float22bfloat162_rn(make_float2(aB[2*ks].z,   aB[2*ks].w));
                u.h2[2] = __float22bfloat162_rn(make_float2(aB[2*ks+1].x, aB[2*ks+1].y));
                u.h2[3] = __float22bfloat162_rn(make_float2(aB[2*ks+1].z, aB[2*ks+1].w));
                #pragma unroll
                for (int nt = 0; nt < 4; ++nt) {
                    const bf16x8 bf = *(const bf16x8*)(wb_base + nt * 16 * (EB + 8) + ks * 32);
                    acc[nt] = __builtin_amdgcn_mfma_f32_16x16x32_bf16(u.v, bf, acc[nt], 0, 0, 0);
                }
            }
            float part[4];
            #pragma unroll
            for (int r = 0; r < 4; ++r) {
                float s = 0.f;
                #pragma unroll
                for (int nt = 0; nt < 4; ++nt) {
                    float hv = acc[nt][r] + biasq[nt];
                    hv = hv > 0.f ? hv : 0.f;
                    s += hv * w1q[nt];
                }
                part[r] = s;
            }
            #pragma unroll
            for (int m = 1; m < 16; m <<= 1) {
                #pragma unroll
                for (int r = 0; r < 4; ++r)
                    part[r] += __shfl_xor(part[r], m, 64);
            }
            if (ln15 == 0) {
                #pragma unroll
                for (int r = 0; r < 4; ++r) {
                    const int mg = mtB * 16 + quad * 4 + r;
                    if (mg < TB) out[(size_t)b * TB + mg] = part[r] + b1v;
                }
            }
        }
    }
}

extern "C" void kernel_launch(void* const* d_in, const int* in_sizes, int n_in,
                              void* d_out, int out_size, void* d_ws, size_t ws_size,
                              hipStream_t stream) {
    const float* query = (const float*)d_in[0];
    const float* keys  = (const float*)d_in[1];
    const float* W0    = (const float*)d_in[2];
    const float* b0    = (const float*)d_in[3];
    const float* W1    = (const float*)d_in[4];
    const float* b1    = (const float*)d_in[5];
    float* out = (float*)d_out;

    lau_kernel<<<1024, 256, 0, stream>>>(query, keys, W0, b0, W1, b1, out);
}

// Round 9
// 167.618 us; speedup vs baseline: 1.3086x; 1.1383x over previous
//
#include <hip/hip_runtime.h>
#include <hip/hip_bf16.h>

// LocalActivationUnit: score[b,t] = relu([q,k,q-k,q*k]·W0 + b0)·W1 + b1
// Folded form: Wb[e][h] = W0[128+e][h] - W0[256+e][h] + q[e]*W0[384+e][h]
//              bias[h]  = sum_e q[e]*(W0[e][h] + W0[256+e][h]) + b0[h]
//              h = relu(k·Wb + bias);  score = h·W1 + b1
//
// R9 (5th submit; rounds 5-8 all hit GPUAcquisitionTimeout — never ran):
// copy-shaped key streaming. Evidence: every register-direct variant
// converges to 1.7-2.9 TB/s effective key-stream rate (R0 48us..R7 91us)
// with >90% memory stall, while the same chip's contiguous float4 copy does
// 6.3 TB/s and the harness's own fill does 6.8 TB/s. The difference is the
// access shape: 16-row scattered 8KB bursts with long dead time vs contiguous
// continuously-pipelined streams. This version:
//  - one 512-thread block per batch (__launch_bounds__(512,4): 2 blocks/CU,
//    1024 blocks = two clean full-chip rounds, VGPR cap 128)
//  - fold unchanged (R0 form, 8 e-chunks of 16)
//  - B-fragments (WbT) hoisted to 64 VGPRs once; LDS region then REUSED:
//    keys[b] streamed with fully CONTIGUOUS lane-consecutive float4 loads
//    (two half-batches, ~7 loads in flight/thread), converted to bf16,
//    staged into kt[208][136] (272-B rows = the proven conflict-free stride)
//  - MFMA tiles read A-fragments from LDS; epilogue byte-identical to R0

#define TB 200
#define EB 128
#define HB 64
#define KROW 136            // padded bf16 row: 272 B (16B-aligned b128 frags)
#define KROWS 208           // 13 tiles * 16 rows (200 valid, 8 junk, masked)

typedef __attribute__((ext_vector_type(8))) short bf16x8;
typedef __attribute__((ext_vector_type(4))) float f32x4;

__global__ __launch_bounds__(512, 4)
void lau_kernel(const float* __restrict__ query,
                const float* __restrict__ keys,
                const float* __restrict__ W0,
                const float* __restrict__ b0,
                const float* __restrict__ W1,
                const float* __restrict__ b1,
                float* __restrict__ out)
{
    const int b    = blockIdx.x;
    const int tid  = threadIdx.x;
    const int lane = tid & 63;
    const int wave = tid >> 6;          // 0..7
    const int ln15 = lane & 15;
    const int quad = lane >> 4;

    __shared__ float bias_s[HB];
    __shared__ float w1_s[HB];
    // Union region: phase A = q_s(512B) + red_s(2048B) + wbt(17408B) = 19968B;
    // phase B = kt[208][136] bf16 = 56576B. Barrier-separated reuse.
    __shared__ __align__(16) unsigned char smem[KROWS * KROW * 2];

    float* q_s   = (float*)smem;                                   // [128]
    float* red_s = (float*)(smem + 512);                           // [512]
    __hip_bfloat16 (*wbt)[KROW] = (__hip_bfloat16(*)[KROW])(smem + 2560);
    __hip_bfloat16 (*kt)[KROW]  = (__hip_bfloat16(*)[KROW])smem;

    const float* kb = keys + (size_t)b * TB * EB;

    if (tid < EB) q_s[tid] = query[(size_t)b * EB + tid];
    __syncthreads();

    // ---- per-batch weight fold + bias partials (R0 form, 8 chunks) ----
    {
        const int h     = tid & 63;
        const int chunk = tid >> 6;       // 0..7, each covers 16 e's
        float biasp = 0.f;
        #pragma unroll 8
        for (int i = 0; i < 16; ++i) {
            const int e = chunk * 16 + i;
            const float qe  = q_s[e];
            const float w0a = W0[(size_t)e            * HB + h];
            const float w0b = W0[(size_t)(EB + e)     * HB + h];
            const float w0c = W0[(size_t)(2 * EB + e) * HB + h];
            const float w0d = W0[(size_t)(3 * EB + e) * HB + h];
            wbt[h][e] = __float2bfloat16(w0b - w0c + qe * w0d);
            biasp += qe * (w0a + w0c);
        }
        red_s[tid] = biasp;
    }
    __syncthreads();
    if (tid < HB) {
        float s = b0[tid];
        #pragma unroll
        for (int j = 0; j < 8; ++j) s += red_s[tid + 64 * j];
        bias_s[tid] = s;
        w1_s[tid]   = W1[tid];
    }
    __syncthreads();

    // ---- issue half-1 of the key stream (rows 0..99), fully contiguous:
    // 16-B unit u -> lane-consecutive addresses, 1 KB per wave-instr ----
    float4 g[7];
    #pragma unroll
    for (int j = 0; j < 7; ++j) {
        const int u = tid + j * 512;                 // unit within half (3200)
        if (u < 3200) g[j] = *(const float4*)(kb + (size_t)u * 4);
    }

    // ---- hoist B-fragments + per-lane bias/w1 while loads are in flight ----
    bf16x8 wbf[4][4];
    #pragma unroll
    for (int nt = 0; nt < 4; ++nt)
        #pragma unroll
        for (int ks = 0; ks < 4; ++ks)
            wbf[nt][ks] = *(const bf16x8*)&wbt[nt * 16 + ln15][quad * 8 + ks * 32];
    float w1q[4], biasq[4];
    #pragma unroll
    for (int nt = 0; nt < 4; ++nt) {
        w1q[nt]   = w1_s[nt * 16 + ln15];
        biasq[nt] = bias_s[nt * 16 + ln15];
    }

    __syncthreads();   // all wbt reads done; barrier drain lands half-1 loads

    // ---- write half-1 to kt; issue half-2; write half-2 ----
    #pragma unroll
    for (int j = 0; j < 7; ++j) {
        const int u = tid + j * 512;
        if (u < 3200) {
            const int row  = u >> 5;            // 32 units per 512-B row
            const int col4 = (u & 31) * 4;      // float column
            union { uint2 w; __hip_bfloat162 h2[2]; } pk;
            pk.h2[0] = __float22bfloat162_rn(make_float2(g[j].x, g[j].y));
            pk.h2[1] = __float22bfloat162_rn(make_float2(g[j].z, g[j].w));
            *(uint2*)&kt[row][col4] = pk.w;     // 8-B aligned: 272r + 8*(col4/4)
        }
    }
    #pragma unroll
    for (int j = 0; j < 7; ++j) {
        const int u = 3200 + tid + j * 512;
        if (u < 6400) g[j] = *(const float4*)(kb + (size_t)u * 4);
    }
    #pragma unroll
    for (int j = 0; j < 7; ++j) {
        const int u = 3200 + tid + j * 512;
        if (u < 6400) {
            const int row  = u >> 5;
            const int col4 = (u & 31) * 4;
            union { uint2 w; __hip_bfloat162 h2[2]; } pk;
            pk.h2[0] = __float22bfloat162_rn(make_float2(g[j].x, g[j].y));
            pk.h2[1] = __float22bfloat162_rn(make_float2(g[j].z, g[j].w));
            *(uint2*)&kt[row][col4] = pk.w;
        }
    }
    __syncthreads();

    // ---- MFMA tiles from LDS (rows 200..207 are junk, outputs masked) ----
    const float b1v = b1[0];
    for (int mt = wave; mt < 13; mt += 8) {
        bf16x8 af[4];
        #pragma unroll
        for (int ks = 0; ks < 4; ++ks)
            af[ks] = *(const bf16x8*)&kt[mt * 16 + ln15][quad * 8 + ks * 32];

        f32x4 acc[4] = {{0,0,0,0},{0,0,0,0},{0,0,0,0},{0,0,0,0}};
        #pragma unroll
        for (int ks = 0; ks < 4; ++ks)
            #pragma unroll
            for (int nt = 0; nt < 4; ++nt)
                acc[nt] = __builtin_amdgcn_mfma_f32_16x16x32_bf16(af[ks], wbf[nt][ks], acc[nt], 0, 0, 0);

        // ---- epilogue: relu + bias, dot with W1, reduce over n (16 lanes) ----
        // C layout: n = ln15, m(in-tile) = quad*4 + r
        float part[4];
        #pragma unroll
        for (int r = 0; r < 4; ++r) {
            float s = 0.f;
            #pragma unroll
            for (int nt = 0; nt < 4; ++nt) {
                float hv = acc[nt][r] + biasq[nt];
                hv = hv > 0.f ? hv : 0.f;
                s += hv * w1q[nt];
            }
            part[r] = s;
        }
        #pragma unroll
        for (int m = 1; m < 16; m <<= 1) {
            #pragma unroll
            for (int r = 0; r < 4; ++r)
                part[r] += __shfl_xor(part[r], m, 64);
        }
        if (ln15 == 0) {
            #pragma unroll
            for (int r = 0; r < 4; ++r) {
                const int mg = mt * 16 + quad * 4 + r;
                if (mg < TB) out[(size_t)b * TB + mg] = part[r] + b1v;
            }
        }
    }
}

extern "C" void kernel_launch(void* const* d_in, const int* in_sizes, int n_in,
                              void* d_out, int out_size, void* d_ws, size_t ws_size,
                              hipStream_t stream) {
    const float* query = (const float*)d_in[0];
    const float* keys  = (const float*)d_in[1];
    const float* W0    = (const float*)d_in[2];
    const float* b0    = (const float*)d_in[3];
    const float* W1    = (const float*)d_in[4];
    const float* b1    = (const float*)d_in[5];
    float* out = (float*)d_out;

    lau_kernel<<<1024, 512, 0, stream>>>(query, keys, W0, b0, W1, b1, out);
}

// Round 10
// 162.807 us; speedup vs baseline: 1.3473x; 1.0296x over previous
//
#include <hip/hip_runtime.h>
#include <hip/hip_bf16.h>

// LocalActivationUnit: score[b,t] = relu([q,k,q-k,q*k]·W0 + b0)·W1 + b1
// Folded form: Wb[e][h] = W0[128+e][h] - W0[256+e][h] + q[e]*W0[384+e][h]
//              bias[h]  = sum_e q[e]*(W0[e][h] + W0[256+e][h]) + b0[h]
//              h = relu(k·Wb + bias);  score = h·W1 + b1
//
// R10: R9 + NON-TEMPORAL key loads. Evidence: R9 (copy-shaped, massive MLP)
// and R0 (scattered reg-direct) both converge to ~2.3 TB/s key-read rate ->
// neither shape nor concurrency is the limit. Suspect: dirty-L3 writeback
// tax. The harness's 400 MB poison fill leaves Infinity Cache full of dirty
// lines; every key line our kernel ALLOCATES into L3 forces an eviction
// writeback (R6: WRITE_SIZE=46MB with no spills; R7: WRITE=103MB during a
// pure read stream — both are the eviction signature). __builtin_
// nontemporal_load (nt) reads without allocating -> no eviction stream.
// Everything else byte-identical to R9 (one-variable experiment).
// Prediction: kernel 45.6 -> 20-30us, dur 142-152, kernel FETCH ~100MB,
// kernel WRITE ~1MB. If dur >= 164: theory dead, R0/R9 is the platform
// ceiling, declare ROOFLINE next round.

#define TB 200
#define EB 128
#define HB 64
#define KROW 136            // padded bf16 row: 272 B (16B-aligned b128 frags)
#define KROWS 208           // 13 tiles * 16 rows (200 valid, 8 junk, masked)

typedef __attribute__((ext_vector_type(8))) short bf16x8;
typedef __attribute__((ext_vector_type(4))) float f32x4;

__global__ __launch_bounds__(512, 4)
void lau_kernel(const float* __restrict__ query,
                const float* __restrict__ keys,
                const float* __restrict__ W0,
                const float* __restrict__ b0,
                const float* __restrict__ W1,
                const float* __restrict__ b1,
                float* __restrict__ out)
{
    const int b    = blockIdx.x;
    const int tid  = threadIdx.x;
    const int lane = tid & 63;
    const int wave = tid >> 6;          // 0..7
    const int ln15 = lane & 15;
    const int quad = lane >> 4;

    __shared__ float bias_s[HB];
    __shared__ float w1_s[HB];
    // Union region: phase A = q_s(512B) + red_s(2048B) + wbt(17408B) = 19968B;
    // phase B = kt[208][136] bf16 = 56576B. Barrier-separated reuse.
    __shared__ __align__(16) unsigned char smem[KROWS * KROW * 2];

    float* q_s   = (float*)smem;                                   // [128]
    float* red_s = (float*)(smem + 512);                           // [512]
    __hip_bfloat16 (*wbt)[KROW] = (__hip_bfloat16(*)[KROW])(smem + 2560);
    __hip_bfloat16 (*kt)[KROW]  = (__hip_bfloat16(*)[KROW])smem;

    const float* kb = keys + (size_t)b * TB * EB;

    if (tid < EB) q_s[tid] = query[(size_t)b * EB + tid];
    __syncthreads();

    // ---- per-batch weight fold + bias partials (R0 form, 8 chunks) ----
    {
        const int h     = tid & 63;
        const int chunk = tid >> 6;       // 0..7, each covers 16 e's
        float biasp = 0.f;
        #pragma unroll 8
        for (int i = 0; i < 16; ++i) {
            const int e = chunk * 16 + i;
            const float qe  = q_s[e];
            const float w0a = W0[(size_t)e            * HB + h];
            const float w0b = W0[(size_t)(EB + e)     * HB + h];
            const float w0c = W0[(size_t)(2 * EB + e) * HB + h];
            const float w0d = W0[(size_t)(3 * EB + e) * HB + h];
            wbt[h][e] = __float2bfloat16(w0b - w0c + qe * w0d);
            biasp += qe * (w0a + w0c);
        }
        red_s[tid] = biasp;
    }
    __syncthreads();
    if (tid < HB) {
        float s = b0[tid];
        #pragma unroll
        for (int j = 0; j < 8; ++j) s += red_s[tid + 64 * j];
        bias_s[tid] = s;
        w1_s[tid]   = W1[tid];
    }
    __syncthreads();

    // ---- issue half-1 of the key stream (rows 0..99), fully contiguous,
    // NON-TEMPORAL: no L3 allocation -> no dirty-fill eviction writebacks ----
    f32x4 g[7];
    #pragma unroll
    for (int j = 0; j < 7; ++j) {
        const int u = tid + j * 512;                 // unit within half (3200)
        if (u < 3200) g[j] = __builtin_nontemporal_load((const f32x4*)(kb + (size_t)u * 4));
    }

    // ---- hoist B-fragments + per-lane bias/w1 while loads are in flight ----
    bf16x8 wbf[4][4];
    #pragma unroll
    for (int nt = 0; nt < 4; ++nt)
        #pragma unroll
        for (int ks = 0; ks < 4; ++ks)
            wbf[nt][ks] = *(const bf16x8*)&wbt[nt * 16 + ln15][quad * 8 + ks * 32];
    float w1q[4], biasq[4];
    #pragma unroll
    for (int nt = 0; nt < 4; ++nt) {
        w1q[nt]   = w1_s[nt * 16 + ln15];
        biasq[nt] = bias_s[nt * 16 + ln15];
    }

    __syncthreads();   // all wbt reads done; barrier drain lands half-1 loads

    // ---- write half-1 to kt; issue half-2; write half-2 ----
    #pragma unroll
    for (int j = 0; j < 7; ++j) {
        const int u = tid + j * 512;
        if (u < 3200) {
            const int row  = u >> 5;            // 32 units per 512-B row
            const int col4 = (u & 31) * 4;      // float column
            union { uint2 w; __hip_bfloat162 h2[2]; } pk;
            pk.h2[0] = __float22bfloat162_rn(make_float2(g[j][0], g[j][1]));
            pk.h2[1] = __float22bfloat162_rn(make_float2(g[j][2], g[j][3]));
            *(uint2*)&kt[row][col4] = pk.w;     // 8-B aligned: 272r + 8*(col4/4)
        }
    }
    #pragma unroll
    for (int j = 0; j < 7; ++j) {
        const int u = 3200 + tid + j * 512;
        if (u < 6400) g[j] = __builtin_nontemporal_load((const f32x4*)(kb + (size_t)u * 4));
    }
    #pragma unroll
    for (int j = 0; j < 7; ++j) {
        const int u = 3200 + tid + j * 512;
        if (u < 6400) {
            const int row  = u >> 5;
            const int col4 = (u & 31) * 4;
            union { uint2 w; __hip_bfloat162 h2[2]; } pk;
            pk.h2[0] = __float22bfloat162_rn(make_float2(g[j][0], g[j][1]));
            pk.h2[1] = __float22bfloat162_rn(make_float2(g[j][2], g[j][3]));
            *(uint2*)&kt[row][col4] = pk.w;
        }
    }
    __syncthreads();

    // ---- MFMA tiles from LDS (rows 200..207 are junk, outputs masked) ----
    const float b1v = b1[0];
    for (int mt = wave; mt < 13; mt += 8) {
        bf16x8 af[4];
        #pragma unroll
        for (int ks = 0; ks < 4; ++ks)
            af[ks] = *(const bf16x8*)&kt[mt * 16 + ln15][quad * 8 + ks * 32];

        f32x4 acc[4] = {{0,0,0,0},{0,0,0,0},{0,0,0,0},{0,0,0,0}};
        #pragma unroll
        for (int ks = 0; ks < 4; ++ks)
            #pragma unroll
            for (int nt = 0; nt < 4; ++nt)
                acc[nt] = __builtin_amdgcn_mfma_f32_16x16x32_bf16(af[ks], wbf[nt][ks], acc[nt], 0, 0, 0);

        // ---- epilogue: relu + bias, dot with W1, reduce over n (16 lanes) ----
        // C layout: n = ln15, m(in-tile) = quad*4 + r
        float part[4];
        #pragma unroll
        for (int r = 0; r < 4; ++r) {
            float s = 0.f;
            #pragma unroll
            for (int nt = 0; nt < 4; ++nt) {
                float hv = acc[nt][r] + biasq[nt];
                hv = hv > 0.f ? hv : 0.f;
                s += hv * w1q[nt];
            }
            part[r] = s;
        }
        #pragma unroll
        for (int m = 1; m < 16; m <<= 1) {
            #pragma unroll
            for (int r = 0; r < 4; ++r)
                part[r] += __shfl_xor(part[r], m, 64);
        }
        if (ln15 == 0) {
            #pragma unroll
            for (int r = 0; r < 4; ++r) {
                const int mg = mt * 16 + quad * 4 + r;
                if (mg < TB) out[(size_t)b * TB + mg] = part[r] + b1v;
            }
        }
    }
}

extern "C" void kernel_launch(void* const* d_in, const int* in_sizes, int n_in,
                              void* d_out, int out_size, void* d_ws, size_t ws_size,
                              hipStream_t stream) {
    const float* query = (const float*)d_in[0];
    const float* keys  = (const float*)d_in[1];
    const float* W0    = (const float*)d_in[2];
    const float* b0    = (const float*)d_in[3];
    const float* W1    = (const float*)d_in[4];
    const float* b1    = (const float*)d_in[5];
    float* out = (float*)d_out;

    lau_kernel<<<1024, 512, 0, stream>>>(query, keys, W0, b0, W1, b1, out);
}